// Round 5
// baseline (104.379 us; speedup 1.0000x reference)
//
#include <hip/hip_runtime.h>

#define NPTS 4096      // points per cloud
#define NB   4         // batch
#define KP   512       // keypoints
#define HUBER_C 0.01f
#define HALF_PTS (NB * NPTS)          // 16384
#define TOT_PTS  (2 * NB * NPTS)      // 32768
#define GAL_BLOCKS 1024               // 16 qchunk * 8 ostripe * 4 b * 2 dir
#define OSTRIPE 512                   // others per stripe (8 stripes)
// QPT = 1: one query per thread, qchunk = 256

// ws layout:
//   [0,      512 KB)  float4 pts4[TOT_PTS]  {x,y,z,|p|^2}, src then tgt
//   [512 KB, 640 KB)  unsigned minarr[TOT_PTS]
//   [640 KB, +64 B )  ctrl: [0]=float acc (nc loss)

// ---------------- helpers ----------------

__device__ inline void wave_reduce_add_to(float v, float* target) {
    #pragma unroll
    for (int off = 32; off; off >>= 1) v += __shfl_down(v, off, 64);
    if ((threadIdx.x & 63) == 0) atomicAdd(target, v);
}

__device__ inline float huber_f(float x) {
    return (x < HUBER_C) ? 0.5f * x * x
                         : fmaf(HUBER_C, x, -0.5f * HUBER_C * HUBER_C);
}

// ---------------- kernels ----------------

// grid = HALF_PTS/256 = 64 blocks. Builds pts4, inits minarr, zeroes acc.
__global__ __launch_bounds__(256) void prep_kernel(
    const float* __restrict__ srcT, const float* __restrict__ tgtT,
    float4* __restrict__ pts4, unsigned* __restrict__ minarr,
    unsigned* __restrict__ ctrl)
{
    int i = blockIdx.x * 256 + threadIdx.x;    // [0, HALF_PTS)
    int b = i >> 12, j = i & (NPTS - 1);
    const float* s = srcT + b * 3 * NPTS;
    const float* t = tgtT + b * 3 * NPTS;
    float sx = s[j], sy = s[NPTS + j], sz = s[2 * NPTS + j];
    float tx = t[j], ty = t[NPTS + j], tz = t[2 * NPTS + j];
    pts4[i]            = make_float4(sx, sy, sz, fmaf(sx, sx, fmaf(sy, sy, sz * sz)));
    pts4[HALF_PTS + i] = make_float4(tx, ty, tz, fmaf(tx, tx, fmaf(ty, ty, tz * tz)));
    minarr[i] = 0x7F800000u;                  // +inf
    minarr[HALF_PTS + i] = 0x7F800000u;
    if (i == 0) ctrl[0] = 0u;                 // acc = 0.0f
}

// Fused main: blocks [0,GAL_BLOCKS) gal pairwise-min; then knn; then kp.
__global__ __launch_bounds__(256) void main_kernel(
    const float4* __restrict__ pts4, unsigned* __restrict__ minarr,
    const float* __restrict__ skp, const float* __restrict__ tkp,
    const float* __restrict__ R, const float* __restrict__ T,
    const float* __restrict__ aknn, const float* __restrict__ bknn,
    const int* __restrict__ kptr, float* __restrict__ acc,
    int knn_blocks, int knn_quads)
{
    const int bid = blockIdx.x;
    const int tid = threadIdx.x;

    if (bid < GAL_BLOCKS) {
        // ---- global-align pairwise min ----
        // 1 query/thread, 512-other stripe: 1 atomic per thread total.
        const int oc  = bid & 7;               // 8 other-stripes of 512
        const int b   = (bid >> 3) & 3;
        const int dir = (bid >> 5) & 1;        // 0: queries=src, 1: queries=tgt
        const int qc  = bid >> 6;              // 16 query-chunks of 256
        const float4* q4 = pts4 + (dir ? HALF_PTS : 0) + b * NPTS;
        const float4* o4 = pts4 + (dir ? 0 : HALF_PTS) + b * NPTS + oc * OSTRIPE;
        const int qi = qc * 256 + tid;

        const float4 Q = q4[qi];
        const float ax = -2.0f * Q.x, ay = -2.0f * Q.y, az = -2.0f * Q.z;
        float m = 3.0e38f;

        #pragma unroll 4
        for (int j = 0; j < OSTRIPE; j += 4) {
            float4 o0 = o4[j], o1 = o4[j + 1], o2 = o4[j + 2], o3 = o4[j + 3];
            float t0 = fmaf(o0.x, ax, fmaf(o0.y, ay, fmaf(o0.z, az, o0.w)));
            float t1 = fmaf(o1.x, ax, fmaf(o1.y, ay, fmaf(o1.z, az, o1.w)));
            float t2 = fmaf(o2.x, ax, fmaf(o2.y, ay, fmaf(o2.z, az, o2.w)));
            float t3 = fmaf(o3.x, ax, fmaf(o3.y, ay, fmaf(o3.z, az, o3.w)));
            m = fminf(m, fminf(fminf(t0, t1), fminf(t2, t3)));
        }

        float d = fmaxf(Q.w + m, 0.0f);        // >=0: uint atomicMin order-safe
        atomicMin(&minarr[(dir * NB + b) * NPTS + qi], __float_as_uint(d));
    } else if (bid < GAL_BLOCKS + knn_blocks) {
        // ---- knn consensus: sum((a-b)^2)/k ----
        int i = (bid - GAL_BLOCKS) * 256 + tid;
        float sum = 0.0f;
        if (i < knn_quads) {
            float4 va = ((const float4*)aknn)[i];
            float4 vb = ((const float4*)bknn)[i];
            float dx = va.x - vb.x, dy = va.y - vb.y;
            float dz = va.z - vb.z, dw = va.w - vb.w;
            sum = fmaf(dx, dx, fmaf(dy, dy, fmaf(dz, dz, dw * dw)));
        }
        float scale = 1.0f / (float)(*kptr);
        wave_reduce_add_to(sum * scale, acc);
    } else {
        // ---- keypoints: sum((R@s + t - g)^2) ----
        int i = (bid - GAL_BLOCKS - knn_blocks) * 256 + tid;   // [0, NB*KP)
        int b = i >> 9;
        int n = i & (KP - 1);
        const float* r = R + b * 9;
        const float* t = T + b * 3;
        const float* s = skp + b * 3 * KP;
        const float* g = tkp + b * 3 * KP;
        float sx = s[n], sy = s[KP + n], sz = s[2 * KP + n];
        float sum = 0.0f;
        #pragma unroll
        for (int d = 0; d < 3; ++d) {
            float v = fmaf(r[d*3+0], sx, fmaf(r[d*3+1], sy, fmaf(r[d*3+2], sz, t[d])))
                      - g[d * KP + n];
            sum = fmaf(v, v, sum);
        }
        wave_reduce_add_to(sum, acc);
    }
}

// single block: huber over the 32768 mins, write both outputs
__global__ __launch_bounds__(256) void finalize_kernel(
    const unsigned* __restrict__ minarr, const float* __restrict__ acc,
    float* __restrict__ out)
{
    __shared__ float red[4];
    const int tid = threadIdx.x;
    const uint4* m4 = (const uint4*)minarr;
    float sum = 0.0f;
    #pragma unroll
    for (int r = 0; r < 32; ++r) {           // 256 thr * 32 * uint4 = 32768
        uint4 v = m4[r * 256 + tid];
        sum += huber_f(__uint_as_float(v.x)) + huber_f(__uint_as_float(v.y))
             + huber_f(__uint_as_float(v.z)) + huber_f(__uint_as_float(v.w));
    }
    #pragma unroll
    for (int off = 32; off; off >>= 1) sum += __shfl_down(sum, off, 64);
    if ((tid & 63) == 0) red[tid >> 6] = sum;
    __syncthreads();
    if (tid == 0) {
        out[1] = red[0] + red[1] + red[2] + red[3];  // gal
        out[0] = *acc;                               // neighborhood consensus
    }
}

// ---------------- fallback (no workspace) ----------------

__global__ void zero_out_kernel(float* __restrict__ out) {
    if (threadIdx.x < 2) out[threadIdx.x] = 0.0f;
}

__global__ __launch_bounds__(256) void gal_direct_kernel(
    const float* __restrict__ srcT, const float* __restrict__ tgtT,
    float* __restrict__ gal_out)
{
    const int dir = blockIdx.y >> 2;
    const int b   = blockIdx.y & 3;
    const float* qb = (dir ? tgtT : srcT) + b * 3 * NPTS;
    const float* ob = (dir ? srcT : tgtT) + b * 3 * NPTS;
    const int qi = blockIdx.x * 256 + threadIdx.x;
    const float qx = qb[qi], qy = qb[NPTS + qi], qz = qb[2 * NPTS + qi];
    float m = 3.0e38f;
    #pragma unroll 4
    for (int j = 0; j < NPTS; ++j) {
        float dx = qx - ob[j], dy = qy - ob[NPTS + j], dz = qz - ob[2 * NPTS + j];
        m = fminf(m, fmaf(dx, dx, fmaf(dy, dy, dz * dz)));
    }
    wave_reduce_add_to(huber_f(m), gal_out);
}

__global__ __launch_bounds__(256) void kp_kernel(
    const float* __restrict__ skp, const float* __restrict__ tkp,
    const float* __restrict__ R, const float* __restrict__ T,
    float* __restrict__ acc)
{
    int i = blockIdx.x * 256 + threadIdx.x;
    int b = i >> 9, n = i & (KP - 1);
    const float* r = R + b * 9;
    const float* t = T + b * 3;
    const float* s = skp + b * 3 * KP;
    const float* g = tkp + b * 3 * KP;
    float sx = s[n], sy = s[KP + n], sz = s[2 * KP + n];
    float sum = 0.0f;
    #pragma unroll
    for (int d = 0; d < 3; ++d) {
        float v = fmaf(r[d*3+0], sx, fmaf(r[d*3+1], sy, fmaf(r[d*3+2], sz, t[d])))
                  - g[d * KP + n];
        sum = fmaf(v, v, sum);
    }
    wave_reduce_add_to(sum, acc);
}

__global__ __launch_bounds__(256) void knn_kernel(
    const float* __restrict__ a, const float* __restrict__ b,
    const int* __restrict__ kptr, float* __restrict__ acc, int quads)
{
    int i = blockIdx.x * 256 + threadIdx.x;
    float sum = 0.0f;
    if (i < quads) {
        float4 va = ((const float4*)a)[i];
        float4 vb = ((const float4*)b)[i];
        float dx = va.x - vb.x, dy = va.y - vb.y;
        float dz = va.z - vb.z, dw = va.w - vb.w;
        sum = fmaf(dx, dx, fmaf(dy, dy, fmaf(dz, dz, dw * dw)));
    }
    float scale = 1.0f / (float)(*kptr);
    wave_reduce_add_to(sum * scale, acc);
}

// ---------------- launch ----------------

extern "C" void kernel_launch(void* const* d_in, const int* in_sizes, int n_in,
                              void* d_out, int out_size, void* d_ws, size_t ws_size,
                              hipStream_t stream) {
    const float* skp  = (const float*)d_in[0];   // (B,3,KP)
    const float* tkp  = (const float*)d_in[1];   // (B,3,KP)
    const float* R    = (const float*)d_in[2];   // (B,3,3)
    const float* T    = (const float*)d_in[3];   // (B,3)
    const float* aknn = (const float*)d_in[4];   // (B,3,KP,K)
    const float* bknn = (const float*)d_in[5];   // (B,3,KP,K)
    const int*   kptr = (const int*)d_in[6];     // scalar k
    const float* srcT = (const float*)d_in[7];   // (B,3,N)
    const float* tgtT = (const float*)d_in[8];   // (B,3,N)
    float* out = (float*)d_out;

    const int knn_quads  = in_sizes[4] / 4;                 // 49152
    const int knn_blocks = (knn_quads + 255) / 256;         // 192
    const int kp_blocks  = (NB * KP + 255) / 256;           // 8

    const size_t pts_bytes = (size_t)TOT_PTS * 16;          // 512 KB
    const size_t min_bytes = (size_t)TOT_PTS * 4;           // 128 KB
    const size_t ws_need   = pts_bytes + min_bytes + 64;
    if (ws_size >= ws_need) {
        float4*   pts4   = (float4*)d_ws;
        unsigned* minarr = (unsigned*)((char*)d_ws + pts_bytes);
        unsigned* ctrl   = (unsigned*)((char*)d_ws + pts_bytes + min_bytes);
        float*    acc    = (float*)&ctrl[0];
        prep_kernel<<<HALF_PTS / 256, 256, 0, stream>>>(srcT, tgtT, pts4, minarr, ctrl);
        main_kernel<<<GAL_BLOCKS + knn_blocks + kp_blocks, 256, 0, stream>>>(
            pts4, minarr, skp, tkp, R, T, aknn, bknn, kptr, acc,
            knn_blocks, knn_quads);
        finalize_kernel<<<1, 256, 0, stream>>>(minarr, acc, out);
    } else {
        zero_out_kernel<<<1, 64, 0, stream>>>(out);
        gal_direct_kernel<<<dim3(NPTS / 256, 2 * NB), 256, 0, stream>>>(srcT, tgtT, out + 1);
        kp_kernel<<<kp_blocks, 256, 0, stream>>>(skp, tkp, R, T, out);
        knn_kernel<<<knn_blocks, 256, 0, stream>>>(aknn, bknn, kptr, out, knn_quads);
    }
}

// Round 6
// 95.358 us; speedup vs baseline: 1.0946x; 1.0946x over previous
//
#include <hip/hip_runtime.h>

#define NPTS 4096      // points per cloud
#define NB   4         // batch
#define KP   512       // keypoints
#define HUBER_C 0.01f
#define HALF_PTS (NB * NPTS)          // 16384
#define TOT_PTS  (2 * NB * NPTS)      // 32768
#define GAL_BLOCKS 1024               // 4 qchunk * 32 ostripe * 4 b * 2 dir
#define OSTRIPE 128                   // others per stripe (32 stripes)
#define QPT 4                         // queries per thread (qchunk = 1024)

// ws layout:
//   [0,      512 KB)  float4 pts4[TOT_PTS]  {x,y,z,|p|^2}, src then tgt
//   [512 KB, 640 KB)  unsigned minarr[TOT_PTS]
//   [640 KB, +64 B )  ctrl: [0]=float acc (nc loss)

// Tuning log (MI355X):
//   R3: QPT=2, 512 blocks  -> main 49 us (load-latency bound, 15% occ)
//   R4: QPT=4, 1024 blocks -> main ~8-10 us, total 94.8  [best]
//   R5: QPT=1, 1024 blocks -> total 104.4 (4x loads/block; atomics NOT the issue)
//   R6: R4 + 8-wide load batching in gal loop.

// ---------------- helpers ----------------

__device__ inline void wave_reduce_add_to(float v, float* target) {
    #pragma unroll
    for (int off = 32; off; off >>= 1) v += __shfl_down(v, off, 64);
    if ((threadIdx.x & 63) == 0) atomicAdd(target, v);
}

__device__ inline float huber_f(float x) {
    return (x < HUBER_C) ? 0.5f * x * x
                         : fmaf(HUBER_C, x, -0.5f * HUBER_C * HUBER_C);
}

// ---------------- kernels ----------------

// grid = HALF_PTS/256 = 64 blocks. Builds pts4, inits minarr, zeroes acc.
__global__ __launch_bounds__(256) void prep_kernel(
    const float* __restrict__ srcT, const float* __restrict__ tgtT,
    float4* __restrict__ pts4, unsigned* __restrict__ minarr,
    unsigned* __restrict__ ctrl)
{
    int i = blockIdx.x * 256 + threadIdx.x;    // [0, HALF_PTS)
    int b = i >> 12, j = i & (NPTS - 1);
    const float* s = srcT + b * 3 * NPTS;
    const float* t = tgtT + b * 3 * NPTS;
    float sx = s[j], sy = s[NPTS + j], sz = s[2 * NPTS + j];
    float tx = t[j], ty = t[NPTS + j], tz = t[2 * NPTS + j];
    pts4[i]            = make_float4(sx, sy, sz, fmaf(sx, sx, fmaf(sy, sy, sz * sz)));
    pts4[HALF_PTS + i] = make_float4(tx, ty, tz, fmaf(tx, tx, fmaf(ty, ty, tz * tz)));
    minarr[i] = 0x7F800000u;                  // +inf
    minarr[HALF_PTS + i] = 0x7F800000u;
    if (i == 0) ctrl[0] = 0u;                 // acc = 0.0f
}

// Fused main: blocks [0,GAL_BLOCKS) gal pairwise-min; then knn; then kp.
__global__ __launch_bounds__(256) void main_kernel(
    const float4* __restrict__ pts4, unsigned* __restrict__ minarr,
    const float* __restrict__ skp, const float* __restrict__ tkp,
    const float* __restrict__ R, const float* __restrict__ T,
    const float* __restrict__ aknn, const float* __restrict__ bknn,
    const int* __restrict__ kptr, float* __restrict__ acc,
    int knn_blocks, int knn_quads)
{
    const int bid = blockIdx.x;
    const int tid = threadIdx.x;

    if (bid < GAL_BLOCKS) {
        // ---- global-align pairwise min ----
        const int oc  = bid & 31;              // 32 other-stripes of 128
        const int b   = (bid >> 5) & 3;
        const int dir = (bid >> 7) & 1;        // 0: queries=src, 1: queries=tgt
        const int qc  = bid >> 8;              // 4 query-chunks of 1024
        const float4* q4 = pts4 + (dir ? HALF_PTS : 0) + b * NPTS + qc * 1024;
        const float4* o4 = pts4 + (dir ? 0 : HALF_PTS) + b * NPTS + oc * OSTRIPE;

        float ax[QPT], ay[QPT], az[QPT], qw[QPT], mm[QPT];
        #pragma unroll
        for (int q = 0; q < QPT; ++q) {
            float4 Q = q4[tid + q * 256];
            ax[q] = -2.0f * Q.x; ay[q] = -2.0f * Q.y; az[q] = -2.0f * Q.z;
            qw[q] = Q.w; mm[q] = 3.0e38f;
        }

        auto step2 = [&](float4 u, float4 v) {
            #pragma unroll
            for (int q = 0; q < QPT; ++q) {
                float t0 = fmaf(u.x, ax[q], fmaf(u.y, ay[q], fmaf(u.z, az[q], u.w)));
                float t1 = fmaf(v.x, ax[q], fmaf(v.y, ay[q], fmaf(v.z, az[q], v.w)));
                mm[q] = fminf(mm[q], fminf(t0, t1));     // v_min3_f32
            }
        };

        // 8-wide load batching: issue 8 uniform 16B loads, then 112 VALU instr.
        #pragma unroll
        for (int j = 0; j < OSTRIPE; j += 8) {
            float4 o[8];
            #pragma unroll
            for (int u = 0; u < 8; ++u) o[u] = o4[j + u];
            #pragma unroll
            for (int u = 0; u < 8; u += 2) step2(o[u], o[u + 1]);
        }

        unsigned* marr = minarr + (dir * NB + b) * NPTS + qc * 1024 + tid;
        #pragma unroll
        for (int q = 0; q < QPT; ++q) {
            float d = fmaxf(qw[q] + mm[q], 0.0f);   // >=0: uint atomicMin order-safe
            atomicMin(&marr[q * 256], __float_as_uint(d));
        }
    } else if (bid < GAL_BLOCKS + knn_blocks) {
        // ---- knn consensus: sum((a-b)^2)/k ----
        int i = (bid - GAL_BLOCKS) * 256 + tid;
        float sum = 0.0f;
        if (i < knn_quads) {
            float4 va = ((const float4*)aknn)[i];
            float4 vb = ((const float4*)bknn)[i];
            float dx = va.x - vb.x, dy = va.y - vb.y;
            float dz = va.z - vb.z, dw = va.w - vb.w;
            sum = fmaf(dx, dx, fmaf(dy, dy, fmaf(dz, dz, dw * dw)));
        }
        float scale = 1.0f / (float)(*kptr);
        wave_reduce_add_to(sum * scale, acc);
    } else {
        // ---- keypoints: sum((R@s + t - g)^2) ----
        int i = (bid - GAL_BLOCKS - knn_blocks) * 256 + tid;   // [0, NB*KP)
        int b = i >> 9;
        int n = i & (KP - 1);
        const float* r = R + b * 9;
        const float* t = T + b * 3;
        const float* s = skp + b * 3 * KP;
        const float* g = tkp + b * 3 * KP;
        float sx = s[n], sy = s[KP + n], sz = s[2 * KP + n];
        float sum = 0.0f;
        #pragma unroll
        for (int d = 0; d < 3; ++d) {
            float v = fmaf(r[d*3+0], sx, fmaf(r[d*3+1], sy, fmaf(r[d*3+2], sz, t[d])))
                      - g[d * KP + n];
            sum = fmaf(v, v, sum);
        }
        wave_reduce_add_to(sum, acc);
    }
}

// single block: huber over the 32768 mins, write both outputs
__global__ __launch_bounds__(256) void finalize_kernel(
    const unsigned* __restrict__ minarr, const float* __restrict__ acc,
    float* __restrict__ out)
{
    __shared__ float red[4];
    const int tid = threadIdx.x;
    const uint4* m4 = (const uint4*)minarr;
    float sum = 0.0f;
    #pragma unroll
    for (int r = 0; r < 32; ++r) {           // 256 thr * 32 * uint4 = 32768
        uint4 v = m4[r * 256 + tid];
        sum += huber_f(__uint_as_float(v.x)) + huber_f(__uint_as_float(v.y))
             + huber_f(__uint_as_float(v.z)) + huber_f(__uint_as_float(v.w));
    }
    #pragma unroll
    for (int off = 32; off; off >>= 1) sum += __shfl_down(sum, off, 64);
    if ((tid & 63) == 0) red[tid >> 6] = sum;
    __syncthreads();
    if (tid == 0) {
        out[1] = red[0] + red[1] + red[2] + red[3];  // gal
        out[0] = *acc;                               // neighborhood consensus
    }
}

// ---------------- fallback (no workspace) ----------------

__global__ void zero_out_kernel(float* __restrict__ out) {
    if (threadIdx.x < 2) out[threadIdx.x] = 0.0f;
}

__global__ __launch_bounds__(256) void gal_direct_kernel(
    const float* __restrict__ srcT, const float* __restrict__ tgtT,
    float* __restrict__ gal_out)
{
    const int dir = blockIdx.y >> 2;
    const int b   = blockIdx.y & 3;
    const float* qb = (dir ? tgtT : srcT) + b * 3 * NPTS;
    const float* ob = (dir ? srcT : tgtT) + b * 3 * NPTS;
    const int qi = blockIdx.x * 256 + threadIdx.x;
    const float qx = qb[qi], qy = qb[NPTS + qi], qz = qb[2 * NPTS + qi];
    float m = 3.0e38f;
    #pragma unroll 4
    for (int j = 0; j < NPTS; ++j) {
        float dx = qx - ob[j], dy = qy - ob[NPTS + j], dz = qz - ob[2 * NPTS + j];
        m = fminf(m, fmaf(dx, dx, fmaf(dy, dy, dz * dz)));
    }
    wave_reduce_add_to(huber_f(m), gal_out);
}

__global__ __launch_bounds__(256) void kp_kernel(
    const float* __restrict__ skp, const float* __restrict__ tkp,
    const float* __restrict__ R, const float* __restrict__ T,
    float* __restrict__ acc)
{
    int i = blockIdx.x * 256 + threadIdx.x;
    int b = i >> 9, n = i & (KP - 1);
    const float* r = R + b * 9;
    const float* t = T + b * 3;
    const float* s = skp + b * 3 * KP;
    const float* g = tkp + b * 3 * KP;
    float sx = s[n], sy = s[KP + n], sz = s[2 * KP + n];
    float sum = 0.0f;
    #pragma unroll
    for (int d = 0; d < 3; ++d) {
        float v = fmaf(r[d*3+0], sx, fmaf(r[d*3+1], sy, fmaf(r[d*3+2], sz, t[d])))
                  - g[d * KP + n];
        sum = fmaf(v, v, sum);
    }
    wave_reduce_add_to(sum, acc);
}

__global__ __launch_bounds__(256) void knn_kernel(
    const float* __restrict__ a, const float* __restrict__ b,
    const int* __restrict__ kptr, float* __restrict__ acc, int quads)
{
    int i = blockIdx.x * 256 + threadIdx.x;
    float sum = 0.0f;
    if (i < quads) {
        float4 va = ((const float4*)a)[i];
        float4 vb = ((const float4*)b)[i];
        float dx = va.x - vb.x, dy = va.y - vb.y;
        float dz = va.z - vb.z, dw = va.w - vb.w;
        sum = fmaf(dx, dx, fmaf(dy, dy, fmaf(dz, dz, dw * dw)));
    }
    float scale = 1.0f / (float)(*kptr);
    wave_reduce_add_to(sum * scale, acc);
}

// ---------------- launch ----------------

extern "C" void kernel_launch(void* const* d_in, const int* in_sizes, int n_in,
                              void* d_out, int out_size, void* d_ws, size_t ws_size,
                              hipStream_t stream) {
    const float* skp  = (const float*)d_in[0];   // (B,3,KP)
    const float* tkp  = (const float*)d_in[1];   // (B,3,KP)
    const float* R    = (const float*)d_in[2];   // (B,3,3)
    const float* T    = (const float*)d_in[3];   // (B,3)
    const float* aknn = (const float*)d_in[4];   // (B,3,KP,K)
    const float* bknn = (const float*)d_in[5];   // (B,3,KP,K)
    const int*   kptr = (const int*)d_in[6];     // scalar k
    const float* srcT = (const float*)d_in[7];   // (B,3,N)
    const float* tgtT = (const float*)d_in[8];   // (B,3,N)
    float* out = (float*)d_out;

    const int knn_quads  = in_sizes[4] / 4;                 // 49152
    const int knn_blocks = (knn_quads + 255) / 256;         // 192
    const int kp_blocks  = (NB * KP + 255) / 256;           // 8

    const size_t pts_bytes = (size_t)TOT_PTS * 16;          // 512 KB
    const size_t min_bytes = (size_t)TOT_PTS * 4;           // 128 KB
    const size_t ws_need   = pts_bytes + min_bytes + 64;
    if (ws_size >= ws_need) {
        float4*   pts4   = (float4*)d_ws;
        unsigned* minarr = (unsigned*)((char*)d_ws + pts_bytes);
        unsigned* ctrl   = (unsigned*)((char*)d_ws + pts_bytes + min_bytes);
        float*    acc    = (float*)&ctrl[0];
        prep_kernel<<<HALF_PTS / 256, 256, 0, stream>>>(srcT, tgtT, pts4, minarr, ctrl);
        main_kernel<<<GAL_BLOCKS + knn_blocks + kp_blocks, 256, 0, stream>>>(
            pts4, minarr, skp, tkp, R, T, aknn, bknn, kptr, acc,
            knn_blocks, knn_quads);
        finalize_kernel<<<1, 256, 0, stream>>>(minarr, acc, out);
    } else {
        zero_out_kernel<<<1, 64, 0, stream>>>(out);
        gal_direct_kernel<<<dim3(NPTS / 256, 2 * NB), 256, 0, stream>>>(srcT, tgtT, out + 1);
        kp_kernel<<<kp_blocks, 256, 0, stream>>>(skp, tkp, R, T, out);
        knn_kernel<<<knn_blocks, 256, 0, stream>>>(aknn, bknn, kptr, out, knn_quads);
    }
}

// Round 7
// 93.275 us; speedup vs baseline: 1.1190x; 1.0223x over previous
//
#include <hip/hip_runtime.h>

#define NPTS 4096      // points per cloud
#define NB   4         // batch
#define KP   512       // keypoints
#define HUBER_C 0.01f
#define HALF_PTS (NB * NPTS)          // 16384
#define TOT_PTS  (2 * NB * NPTS)      // 32768
#define GAL_BLOCKS 1024               // 4 qchunk * 32 ostripe * 4 b * 2 dir
#define OSTRIPE 128                   // others per stripe (32 stripes)
#define QPT 4                         // queries per thread (qchunk = 1024)

typedef float v2f __attribute__((ext_vector_type(2)));

// ws layout:
//   [0,      512 KB)  float4 pts4[TOT_PTS]  {x,y,z,|p|^2}, src then tgt
//   [512 KB, 640 KB)  unsigned minarr[TOT_PTS]
//   [640 KB, +64 B )  ctrl: [0]=float acc (nc loss)

// Tuning log (MI355X):
//   R3: QPT=2, 512 blocks  -> main 49 us (load-latency bound, 15% occ)
//   R4: QPT=4, 1024 blocks -> total 94.8  [prev best]
//   R5: QPT=1, 1024 blocks -> 104.4 (loads/block 4x; atomics NOT the issue)
//   R6: R4 + 8-wide load batch -> 95.4 (neutral; latency already covered)
//   R7: R4 + packed-fp32 (v_pk_fma_f32) inner loop: 14 -> 8 instr per (o,4q).

// ---------------- helpers ----------------

__device__ inline void wave_reduce_add_to(float v, float* target) {
    #pragma unroll
    for (int off = 32; off; off >>= 1) v += __shfl_down(v, off, 64);
    if ((threadIdx.x & 63) == 0) atomicAdd(target, v);
}

__device__ inline float huber_f(float x) {
    return (x < HUBER_C) ? 0.5f * x * x
                         : fmaf(HUBER_C, x, -0.5f * HUBER_C * HUBER_C);
}

__device__ inline v2f splat2(float s) { v2f r; r.x = s; r.y = s; return r; }

// ---------------- kernels ----------------

// grid = HALF_PTS/256 = 64 blocks. Builds pts4, inits minarr, zeroes acc.
__global__ __launch_bounds__(256) void prep_kernel(
    const float* __restrict__ srcT, const float* __restrict__ tgtT,
    float4* __restrict__ pts4, unsigned* __restrict__ minarr,
    unsigned* __restrict__ ctrl)
{
    int i = blockIdx.x * 256 + threadIdx.x;    // [0, HALF_PTS)
    int b = i >> 12, j = i & (NPTS - 1);
    const float* s = srcT + b * 3 * NPTS;
    const float* t = tgtT + b * 3 * NPTS;
    float sx = s[j], sy = s[NPTS + j], sz = s[2 * NPTS + j];
    float tx = t[j], ty = t[NPTS + j], tz = t[2 * NPTS + j];
    pts4[i]            = make_float4(sx, sy, sz, fmaf(sx, sx, fmaf(sy, sy, sz * sz)));
    pts4[HALF_PTS + i] = make_float4(tx, ty, tz, fmaf(tx, tx, fmaf(ty, ty, tz * tz)));
    minarr[i] = 0x7F800000u;                  // +inf
    minarr[HALF_PTS + i] = 0x7F800000u;
    if (i == 0) ctrl[0] = 0u;                 // acc = 0.0f
}

// Fused main: blocks [0,GAL_BLOCKS) gal pairwise-min; then knn; then kp.
__global__ __launch_bounds__(256) void main_kernel(
    const float4* __restrict__ pts4, unsigned* __restrict__ minarr,
    const float* __restrict__ skp, const float* __restrict__ tkp,
    const float* __restrict__ R, const float* __restrict__ T,
    const float* __restrict__ aknn, const float* __restrict__ bknn,
    const int* __restrict__ kptr, float* __restrict__ acc,
    int knn_blocks, int knn_quads)
{
    const int bid = blockIdx.x;
    const int tid = threadIdx.x;

    if (bid < GAL_BLOCKS) {
        // ---- global-align pairwise min ----
        const int oc  = bid & 31;              // 32 other-stripes of 128
        const int b   = (bid >> 5) & 3;
        const int dir = (bid >> 7) & 1;        // 0: queries=src, 1: queries=tgt
        const int qc  = bid >> 8;              // 4 query-chunks of 1024
        const float4* q4 = pts4 + (dir ? HALF_PTS : 0) + b * NPTS + qc * 1024;
        const float4* o4 = pts4 + (dir ? 0 : HALF_PTS) + b * NPTS + oc * OSTRIPE;

        // 4 queries packed as 2 float2 pairs: p in {0,1}, lanes {2p, 2p+1}
        v2f ax2[2], ay2[2], az2[2], mm2[2];
        float qw[QPT];
        #pragma unroll
        for (int p = 0; p < 2; ++p) {
            float4 Qa = q4[tid + (2 * p) * 256];
            float4 Qb = q4[tid + (2 * p + 1) * 256];
            ax2[p].x = -2.0f * Qa.x; ax2[p].y = -2.0f * Qb.x;
            ay2[p].x = -2.0f * Qa.y; ay2[p].y = -2.0f * Qb.y;
            az2[p].x = -2.0f * Qa.z; az2[p].y = -2.0f * Qb.z;
            qw[2 * p] = Qa.w; qw[2 * p + 1] = Qb.w;
            mm2[p].x = 3.0e38f; mm2[p].y = 3.0e38f;
        }

        // per o-pair per q-pair: 6 v_pk_fma_f32 + 2 v_min3_f32
        auto step2 = [&](const float4& u, const float4& v) {
            #pragma unroll
            for (int p = 0; p < 2; ++p) {
                v2f t0 = __builtin_elementwise_fma(splat2(u.x), ax2[p],
                         __builtin_elementwise_fma(splat2(u.y), ay2[p],
                         __builtin_elementwise_fma(splat2(u.z), az2[p], splat2(u.w))));
                v2f t1 = __builtin_elementwise_fma(splat2(v.x), ax2[p],
                         __builtin_elementwise_fma(splat2(v.y), ay2[p],
                         __builtin_elementwise_fma(splat2(v.z), az2[p], splat2(v.w))));
                mm2[p].x = fminf(mm2[p].x, fminf(t0.x, t1.x));   // v_min3_f32
                mm2[p].y = fminf(mm2[p].y, fminf(t0.y, t1.y));
            }
        };

        #pragma unroll 4
        for (int j = 0; j < OSTRIPE; j += 4) {
            float4 o0 = o4[j], o1 = o4[j + 1], o2 = o4[j + 2], o3 = o4[j + 3];
            step2(o0, o1);
            step2(o2, o3);
        }

        unsigned* marr = minarr + (dir * NB + b) * NPTS + qc * 1024 + tid;
        #pragma unroll
        for (int p = 0; p < 2; ++p) {
            float d0 = fmaxf(qw[2 * p]     + mm2[p].x, 0.0f);  // >=0: atomicMin-safe
            float d1 = fmaxf(qw[2 * p + 1] + mm2[p].y, 0.0f);
            atomicMin(&marr[(2 * p) * 256],     __float_as_uint(d0));
            atomicMin(&marr[(2 * p + 1) * 256], __float_as_uint(d1));
        }
    } else if (bid < GAL_BLOCKS + knn_blocks) {
        // ---- knn consensus: sum((a-b)^2)/k ----
        int i = (bid - GAL_BLOCKS) * 256 + tid;
        float sum = 0.0f;
        if (i < knn_quads) {
            float4 va = ((const float4*)aknn)[i];
            float4 vb = ((const float4*)bknn)[i];
            float dx = va.x - vb.x, dy = va.y - vb.y;
            float dz = va.z - vb.z, dw = va.w - vb.w;
            sum = fmaf(dx, dx, fmaf(dy, dy, fmaf(dz, dz, dw * dw)));
        }
        float scale = 1.0f / (float)(*kptr);
        wave_reduce_add_to(sum * scale, acc);
    } else {
        // ---- keypoints: sum((R@s + t - g)^2) ----
        int i = (bid - GAL_BLOCKS - knn_blocks) * 256 + tid;   // [0, NB*KP)
        int b = i >> 9;
        int n = i & (KP - 1);
        const float* r = R + b * 9;
        const float* t = T + b * 3;
        const float* s = skp + b * 3 * KP;
        const float* g = tkp + b * 3 * KP;
        float sx = s[n], sy = s[KP + n], sz = s[2 * KP + n];
        float sum = 0.0f;
        #pragma unroll
        for (int d = 0; d < 3; ++d) {
            float v = fmaf(r[d*3+0], sx, fmaf(r[d*3+1], sy, fmaf(r[d*3+2], sz, t[d])))
                      - g[d * KP + n];
            sum = fmaf(v, v, sum);
        }
        wave_reduce_add_to(sum, acc);
    }
}

// single block: huber over the 32768 mins, write both outputs
__global__ __launch_bounds__(256) void finalize_kernel(
    const unsigned* __restrict__ minarr, const float* __restrict__ acc,
    float* __restrict__ out)
{
    __shared__ float red[4];
    const int tid = threadIdx.x;
    const uint4* m4 = (const uint4*)minarr;
    float sum = 0.0f;
    #pragma unroll
    for (int r = 0; r < 32; ++r) {           // 256 thr * 32 * uint4 = 32768
        uint4 v = m4[r * 256 + tid];
        sum += huber_f(__uint_as_float(v.x)) + huber_f(__uint_as_float(v.y))
             + huber_f(__uint_as_float(v.z)) + huber_f(__uint_as_float(v.w));
    }
    #pragma unroll
    for (int off = 32; off; off >>= 1) sum += __shfl_down(sum, off, 64);
    if ((tid & 63) == 0) red[tid >> 6] = sum;
    __syncthreads();
    if (tid == 0) {
        out[1] = red[0] + red[1] + red[2] + red[3];  // gal
        out[0] = *acc;                               // neighborhood consensus
    }
}

// ---------------- fallback (no workspace) ----------------

__global__ void zero_out_kernel(float* __restrict__ out) {
    if (threadIdx.x < 2) out[threadIdx.x] = 0.0f;
}

__global__ __launch_bounds__(256) void gal_direct_kernel(
    const float* __restrict__ srcT, const float* __restrict__ tgtT,
    float* __restrict__ gal_out)
{
    const int dir = blockIdx.y >> 2;
    const int b   = blockIdx.y & 3;
    const float* qb = (dir ? tgtT : srcT) + b * 3 * NPTS;
    const float* ob = (dir ? srcT : tgtT) + b * 3 * NPTS;
    const int qi = blockIdx.x * 256 + threadIdx.x;
    const float qx = qb[qi], qy = qb[NPTS + qi], qz = qb[2 * NPTS + qi];
    float m = 3.0e38f;
    #pragma unroll 4
    for (int j = 0; j < NPTS; ++j) {
        float dx = qx - ob[j], dy = qy - ob[NPTS + j], dz = qz - ob[2 * NPTS + j];
        m = fminf(m, fmaf(dx, dx, fmaf(dy, dy, dz * dz)));
    }
    wave_reduce_add_to(huber_f(m), gal_out);
}

__global__ __launch_bounds__(256) void kp_kernel(
    const float* __restrict__ skp, const float* __restrict__ tkp,
    const float* __restrict__ R, const float* __restrict__ T,
    float* __restrict__ acc)
{
    int i = blockIdx.x * 256 + threadIdx.x;
    int b = i >> 9, n = i & (KP - 1);
    const float* r = R + b * 9;
    const float* t = T + b * 3;
    const float* s = skp + b * 3 * KP;
    const float* g = tkp + b * 3 * KP;
    float sx = s[n], sy = s[KP + n], sz = s[2 * KP + n];
    float sum = 0.0f;
    #pragma unroll
    for (int d = 0; d < 3; ++d) {
        float v = fmaf(r[d*3+0], sx, fmaf(r[d*3+1], sy, fmaf(r[d*3+2], sz, t[d])))
                  - g[d * KP + n];
        sum = fmaf(v, v, sum);
    }
    wave_reduce_add_to(sum, acc);
}

__global__ __launch_bounds__(256) void knn_kernel(
    const float* __restrict__ a, const float* __restrict__ b,
    const int* __restrict__ kptr, float* __restrict__ acc, int quads)
{
    int i = blockIdx.x * 256 + threadIdx.x;
    float sum = 0.0f;
    if (i < quads) {
        float4 va = ((const float4*)a)[i];
        float4 vb = ((const float4*)b)[i];
        float dx = va.x - vb.x, dy = va.y - vb.y;
        float dz = va.z - vb.z, dw = va.w - vb.w;
        sum = fmaf(dx, dx, fmaf(dy, dy, fmaf(dz, dz, dw * dw)));
    }
    float scale = 1.0f / (float)(*kptr);
    wave_reduce_add_to(sum * scale, acc);
}

// ---------------- launch ----------------

extern "C" void kernel_launch(void* const* d_in, const int* in_sizes, int n_in,
                              void* d_out, int out_size, void* d_ws, size_t ws_size,
                              hipStream_t stream) {
    const float* skp  = (const float*)d_in[0];   // (B,3,KP)
    const float* tkp  = (const float*)d_in[1];   // (B,3,KP)
    const float* R    = (const float*)d_in[2];   // (B,3,3)
    const float* T    = (const float*)d_in[3];   // (B,3)
    const float* aknn = (const float*)d_in[4];   // (B,3,KP,K)
    const float* bknn = (const float*)d_in[5];   // (B,3,KP,K)
    const int*   kptr = (const int*)d_in[6];     // scalar k
    const float* srcT = (const float*)d_in[7];   // (B,3,N)
    const float* tgtT = (const float*)d_in[8];   // (B,3,N)
    float* out = (float*)d_out;

    const int knn_quads  = in_sizes[4] / 4;                 // 49152
    const int knn_blocks = (knn_quads + 255) / 256;         // 192
    const int kp_blocks  = (NB * KP + 255) / 256;           // 8

    const size_t pts_bytes = (size_t)TOT_PTS * 16;          // 512 KB
    const size_t min_bytes = (size_t)TOT_PTS * 4;           // 128 KB
    const size_t ws_need   = pts_bytes + min_bytes + 64;
    if (ws_size >= ws_need) {
        float4*   pts4   = (float4*)d_ws;
        unsigned* minarr = (unsigned*)((char*)d_ws + pts_bytes);
        unsigned* ctrl   = (unsigned*)((char*)d_ws + pts_bytes + min_bytes);
        float*    acc    = (float*)&ctrl[0];
        prep_kernel<<<HALF_PTS / 256, 256, 0, stream>>>(srcT, tgtT, pts4, minarr, ctrl);
        main_kernel<<<GAL_BLOCKS + knn_blocks + kp_blocks, 256, 0, stream>>>(
            pts4, minarr, skp, tkp, R, T, aknn, bknn, kptr, acc,
            knn_blocks, knn_quads);
        finalize_kernel<<<1, 256, 0, stream>>>(minarr, acc, out);
    } else {
        zero_out_kernel<<<1, 64, 0, stream>>>(out);
        gal_direct_kernel<<<dim3(NPTS / 256, 2 * NB), 256, 0, stream>>>(srcT, tgtT, out + 1);
        kp_kernel<<<kp_blocks, 256, 0, stream>>>(skp, tkp, R, T, out);
        knn_kernel<<<knn_blocks, 256, 0, stream>>>(aknn, bknn, kptr, out, knn_quads);
    }
}